// Round 4
// baseline (701.469 us; speedup 1.0000x reference)
//
#include <hip/hip_runtime.h>
#include <math.h>

// ---------------------------------------------------------------------------
// GCN 2-layer: h1 = relu(gcnconv(x,W1,b1)); out = log_softmax(gcnconv(h1,W2,b2))
// R3: gemm1 via bf16 MFMA; gemm2 fused into agg1 epilogue (shuffle matvec);
// h1,h2 stored bf16; packed {row,norm} edge records; CSR gather (no atomics).
// N=100000, E=1600000, F: 512 -> 64 -> 40
// ---------------------------------------------------------------------------

#define FIN 512
#define FHID 64
#define FOUT 40

typedef __attribute__((ext_vector_type(8))) short short8;
typedef __attribute__((ext_vector_type(4))) float f32x4;
typedef unsigned short ushort_t;
typedef unsigned int uint_t;

__device__ __forceinline__ ushort_t bf16_rn(float f) {
    union { float f; uint_t u; } v; v.f = f;
    uint_t r = v.u + 0x7FFF + ((v.u >> 16) & 1);
    return (ushort_t)(r >> 16);
}
__device__ __forceinline__ uint_t pack_bf16(float a, float b) {
    return (uint_t)bf16_rn(a) | ((uint_t)bf16_rn(b) << 16);
}
__device__ __forceinline__ float bf16_to_f(ushort_t u) {
    union { uint_t i; float f; } t; t.i = ((uint_t)u) << 16; return t.f;
}

// ---------------- histogram of in-degree ----------------
__global__ void hist_kernel(const int* __restrict__ col, int* __restrict__ deg, int E) {
    int e = blockIdx.x * 256 + threadIdx.x;
    if (e < E) atomicAdd(&deg[col[e]], 1);
}

__global__ void dinv_kernel(const int* __restrict__ deg, float* __restrict__ dinv, int n) {
    int i = blockIdx.x * 256 + threadIdx.x;
    if (i < n) dinv[i] = rsqrtf((float)deg[i] + 1.0f);
}

// ---------------- scan ----------------
__global__ void scan1_kernel(const int* __restrict__ deg, int* __restrict__ offs,
                             int* __restrict__ bsums, int n) {
    __shared__ int tmp[256];
    int tid = threadIdx.x;
    int i = blockIdx.x * 256 + tid;
    int v = (i < n) ? deg[i] : 0;
    tmp[tid] = v;
    __syncthreads();
    for (int off = 1; off < 256; off <<= 1) {
        int t = (tid >= off) ? tmp[tid - off] : 0;
        __syncthreads();
        tmp[tid] += t;
        __syncthreads();
    }
    if (i < n) offs[i] = tmp[tid] - v;
    if (tid == 255) bsums[blockIdx.x] = tmp[255];
}

__global__ void scan2_kernel(int* __restrict__ bsums, int nb) {
    __shared__ int tmp[512];
    int tid = threadIdx.x;
    int v = (tid < nb) ? bsums[tid] : 0;
    tmp[tid] = v;
    __syncthreads();
    for (int off = 1; off < 512; off <<= 1) {
        int t = (tid >= off) ? tmp[tid - off] : 0;
        __syncthreads();
        tmp[tid] += t;
        __syncthreads();
    }
    if (tid < nb) bsums[tid] = tmp[tid] - v;
}

__global__ void scan3_kernel(int* __restrict__ offs, const int* __restrict__ bsums,
                             int* __restrict__ cursor, int n) {
    int i = blockIdx.x * 256 + threadIdx.x;
    if (i < n) {
        int o = offs[i] + bsums[blockIdx.x];
        offs[i] = o;
        cursor[i] = o;
    }
}

// ---------------- build dest-sorted packed edge records {row, norm} ----------
__global__ void build_kernel(const int* __restrict__ row, const int* __restrict__ col,
                             const float* __restrict__ dinv, int* __restrict__ cursor,
                             uint2* __restrict__ sEdge, int E) {
    int e = blockIdx.x * 256 + threadIdx.x;
    if (e < E) {
        int r = row[e], c = col[e];
        float nm = dinv[r] * dinv[c];
        int pos = atomicAdd(&cursor[c], 1);
        sEdge[pos] = make_uint2((uint_t)r, __float_as_uint(nm));
    }
}

// ---------------- W1 transpose + bf16: Wt[n][k] = bf16(W1[k][n]) --------------
__global__ void w1t_kernel(const float* __restrict__ W1, ushort_t* __restrict__ Wt) {
    int idx = blockIdx.x * 256 + threadIdx.x;   // 32768
    int nrow = idx >> 9;
    int k = idx & 511;
    Wt[idx] = bf16_rn(W1[k * 64 + nrow]);
}

// ---------------- GEMM1 (MFMA): h1b[N,64] = bf16( x[N,512] @ W1[512,64] ) ----
#define LDA 72
#define LDB 72
__global__ __launch_bounds__(256) void gemm1_kernel(
    const float* __restrict__ x, const ushort_t* __restrict__ Wt,
    ushort_t* __restrict__ h1b, int n) {
    __shared__ ushort_t lA[128 * LDA];
    __shared__ ushort_t lB[64 * LDB];

    int tid = threadIdx.x;
    int wave = tid >> 6, lane = tid & 63;
    int quad = lane >> 4, m16 = lane & 15;
    int node0 = blockIdx.x * 128;

    f32x4 zero = {0.f, 0.f, 0.f, 0.f};
    f32x4 acc[2][4];
#pragma unroll
    for (int mt = 0; mt < 2; ++mt)
#pragma unroll
        for (int nt = 0; nt < 4; ++nt) acc[mt][nt] = zero;

    for (int kc = 0; kc < FIN; kc += 64) {
        __syncthreads();
#pragma unroll
        for (int i = 0; i < 8; ++i) {
            int p = tid + i * 256;
            int r = p >> 4;
            int k4 = p & 15;
            int node = node0 + r;
            float4 v = make_float4(0.f, 0.f, 0.f, 0.f);
            if (node < n) v = *reinterpret_cast<const float4*>(&x[(size_t)node * FIN + kc + k4 * 4]);
            uint2 u = make_uint2(pack_bf16(v.x, v.y), pack_bf16(v.z, v.w));
            *reinterpret_cast<uint2*>(&lA[r * LDA + k4 * 4]) = u;
        }
#pragma unroll
        for (int i = 0; i < 2; ++i) {
            int p = tid + i * 256;
            int nr = p >> 3;
            int seg = p & 7;
            uint4 v = *reinterpret_cast<const uint4*>(&Wt[(size_t)nr * FIN + kc + seg * 8]);
            *reinterpret_cast<uint4*>(&lB[nr * LDB + seg * 8]) = v;
        }
        __syncthreads();
#pragma unroll
        for (int kk = 0; kk < 2; ++kk) {
            short8 a[2], b[4];
#pragma unroll
            for (int mt = 0; mt < 2; ++mt)
                a[mt] = *reinterpret_cast<const short8*>(
                    &lA[(wave * 32 + mt * 16 + m16) * LDA + kk * 32 + quad * 8]);
#pragma unroll
            for (int nt = 0; nt < 4; ++nt)
                b[nt] = *reinterpret_cast<const short8*>(
                    &lB[(nt * 16 + m16) * LDB + kk * 32 + quad * 8]);
#pragma unroll
            for (int mt = 0; mt < 2; ++mt)
#pragma unroll
                for (int nt = 0; nt < 4; ++nt)
                    acc[mt][nt] = __builtin_amdgcn_mfma_f32_16x16x32_bf16(
                        a[mt], b[nt], acc[mt][nt], 0, 0, 0);
        }
    }

#pragma unroll
    for (int mt = 0; mt < 2; ++mt) {
#pragma unroll
        for (int reg = 0; reg < 4; ++reg) {
            int node = node0 + wave * 32 + mt * 16 + quad * 4 + reg;
            if (node < n) {
#pragma unroll
                for (int nt = 0; nt < 4; ++nt)
                    h1b[(size_t)node * 64 + nt * 16 + m16] = bf16_rn(acc[mt][nt][reg]);
            }
        }
    }
}

// ---------------- fused agg1 + self-loop + bias + relu + GEMM2 ----------------
// one wave per node; lane = hidden feature (64); epilogue: h2 = h @ W2 via shfl
__global__ __launch_bounds__(256) void agg1f_kernel(
    const int* __restrict__ offs, const int* __restrict__ deg,
    const uint2* __restrict__ sEdge, const ushort_t* __restrict__ h1b,
    const float* __restrict__ dinv, const float* __restrict__ b1,
    const float* __restrict__ W2, ushort_t* __restrict__ h2b, int n) {
    __shared__ float lw2[64 * FOUT + 64];   // padded for inactive-lane reads
    int tid = threadIdx.x;
#pragma unroll
    for (int r = 0; r < 10; ++r) lw2[tid + r * 256] = W2[tid + r * 256];

    int lane = tid & 63;
    int node = blockIdx.x * 4 + (tid >> 6);
    bool valid = node < n;
    int start = valid ? offs[node] : 0;
    int cnt = valid ? deg[node] : 0;

    float acc0 = 0.f, acc1 = 0.f;
    int k = 0;
    for (; k + 3 < cnt; k += 4) {
        uint2 e0 = sEdge[start + k], e1 = sEdge[start + k + 1];
        uint2 e2 = sEdge[start + k + 2], e3 = sEdge[start + k + 3];
        float v0 = bf16_to_f(h1b[(size_t)e0.x * 64 + lane]);
        float v1 = bf16_to_f(h1b[(size_t)e1.x * 64 + lane]);
        float v2 = bf16_to_f(h1b[(size_t)e2.x * 64 + lane]);
        float v3 = bf16_to_f(h1b[(size_t)e3.x * 64 + lane]);
        acc0 = fmaf(v0, __uint_as_float(e0.y), acc0);
        acc1 = fmaf(v1, __uint_as_float(e1.y), acc1);
        acc0 = fmaf(v2, __uint_as_float(e2.y), acc0);
        acc1 = fmaf(v3, __uint_as_float(e3.y), acc1);
    }
    for (; k < cnt; ++k) {
        uint2 e0 = sEdge[start + k];
        acc0 = fmaf(bf16_to_f(h1b[(size_t)e0.x * 64 + lane]), __uint_as_float(e0.y), acc0);
    }

    float v = 0.f;
    if (valid) {
        float di = dinv[node];
        v = fmaf(bf16_to_f(h1b[(size_t)node * 64 + lane]), di * di, acc0 + acc1) + b1[lane];
        v = fmaxf(v, 0.f);
    }

    __syncthreads();   // lw2 ready (all 256 threads alive)

    // h2[j] = sum_k h[k] * W2[k][j], j = lane (0..39 active)
    float o0 = 0.f, o1 = 0.f;
#pragma unroll
    for (int kk = 0; kk < 64; kk += 4) {
        float a0 = __shfl(v, kk), a1 = __shfl(v, kk + 1);
        float a2 = __shfl(v, kk + 2), a3 = __shfl(v, kk + 3);
        o0 = fmaf(a0, lw2[kk * FOUT + lane], o0);
        o1 = fmaf(a1, lw2[(kk + 1) * FOUT + lane], o1);
        o0 = fmaf(a2, lw2[(kk + 2) * FOUT + lane], o0);
        o1 = fmaf(a3, lw2[(kk + 3) * FOUT + lane], o1);
    }
    if (valid && lane < FOUT)
        h2b[(size_t)node * FOUT + lane] = bf16_rn(o0 + o1);
}

// ---------------- fused agg2 + self-loop + bias + log_softmax ----------------
__global__ __launch_bounds__(256) void agg2_kernel(
    const int* __restrict__ offs, const int* __restrict__ deg,
    const uint2* __restrict__ sEdge, const ushort_t* __restrict__ h2b,
    const float* __restrict__ dinv, const float* __restrict__ b2,
    float* __restrict__ out, int n) {
    int tid = threadIdx.x;
    int lane = tid & 63;
    int node = blockIdx.x * 4 + (tid >> 6);
    if (node >= n) return;            // wave-uniform; no syncs below
    bool act = lane < FOUT;
    int start = offs[node];
    int cnt = deg[node];
    float acc0 = 0.f, acc1 = 0.f;
    int k = 0;
    for (; k + 3 < cnt; k += 4) {
        uint2 e0 = sEdge[start + k], e1 = sEdge[start + k + 1];
        uint2 e2 = sEdge[start + k + 2], e3 = sEdge[start + k + 3];
        float v0 = act ? bf16_to_f(h2b[(size_t)e0.x * FOUT + lane]) : 0.f;
        float v1 = act ? bf16_to_f(h2b[(size_t)e1.x * FOUT + lane]) : 0.f;
        float v2 = act ? bf16_to_f(h2b[(size_t)e2.x * FOUT + lane]) : 0.f;
        float v3 = act ? bf16_to_f(h2b[(size_t)e3.x * FOUT + lane]) : 0.f;
        acc0 = fmaf(v0, __uint_as_float(e0.y), acc0);
        acc1 = fmaf(v1, __uint_as_float(e1.y), acc1);
        acc0 = fmaf(v2, __uint_as_float(e2.y), acc0);
        acc1 = fmaf(v3, __uint_as_float(e3.y), acc1);
    }
    for (; k < cnt; ++k) {
        uint2 e0 = sEdge[start + k];
        float v0 = act ? bf16_to_f(h2b[(size_t)e0.x * FOUT + lane]) : 0.f;
        acc0 = fmaf(v0, __uint_as_float(e0.y), acc0);
    }
    float acc = acc0 + acc1;
    float di = dinv[node];
    float dd = di * di;
    float raw = 0.f, v = -INFINITY;
    if (act) {
        raw = acc + bf16_to_f(h2b[(size_t)node * FOUT + lane]) * dd + b2[lane];
        v = raw;
    }
    float m = v;
#pragma unroll
    for (int off = 32; off > 0; off >>= 1) m = fmaxf(m, __shfl_down(m, off));
    m = __shfl(m, 0);
    float ex = act ? expf(raw - m) : 0.f;
    float s = ex;
#pragma unroll
    for (int off = 32; off > 0; off >>= 1) s += __shfl_down(s, off);
    s = __shfl(s, 0);
    float ls = logf(s);
    if (act) out[(size_t)node * FOUT + lane] = raw - m - ls;
}

// ---------------------------------------------------------------------------
extern "C" void kernel_launch(void* const* d_in, const int* in_sizes, int n_in,
                              void* d_out, int out_size, void* d_ws, size_t ws_size,
                              hipStream_t stream) {
    const float* x  = (const float*)d_in[0];
    const int*   ei = (const int*)d_in[1];
    const float* W1 = (const float*)d_in[2];
    const float* b1 = (const float*)d_in[3];
    const float* W2 = (const float*)d_in[4];
    const float* b2 = (const float*)d_in[5];
    float* out = (float*)d_out;

    int n = in_sizes[0] / FIN;        // 100000
    int E = in_sizes[1] / 2;          // 1600000
    const int* row = ei;
    const int* col = ei + E;

    // workspace layout (4-byte words), ~36 MB total
    int* wsi = (int*)d_ws;
    const size_t NR = 100352;
    int*      deg    = wsi;                                  // [NR]
    float*    dinv   = (float*)(wsi + NR);                   // [NR]
    int*      offs   = wsi + 2 * NR;                         // [NR]
    int*      cursor = wsi + 3 * NR;                         // [NR]
    int*      bsums  = wsi + 4 * NR;                         // [512]
    ushort_t* Wt     = (ushort_t*)(wsi + 4 * NR + 512);      // [64*512] bf16
    uint2*    sEdge  = (uint2*)(wsi + 4 * NR + 512 + 16384); // [E] {row,norm}
    ushort_t* h1b    = (ushort_t*)(sEdge + (size_t)E);       // [n*64] bf16
    ushort_t* h2b    = h1b + (size_t)n * 64;                 // [n*40] bf16

    int nb = (n + 255) / 256;   // 391

    // ---- CSR build ----
    hipMemsetAsync(deg, 0, (size_t)n * 4, stream);
    hist_kernel<<<(E + 255) / 256, 256, 0, stream>>>(col, deg, E);
    dinv_kernel<<<nb, 256, 0, stream>>>(deg, dinv, n);
    scan1_kernel<<<nb, 256, 0, stream>>>(deg, offs, bsums, n);
    scan2_kernel<<<1, 512, 0, stream>>>(bsums, nb);
    scan3_kernel<<<nb, 256, 0, stream>>>(offs, bsums, cursor, n);
    build_kernel<<<(E + 255) / 256, 256, 0, stream>>>(row, col, dinv, cursor, sEdge, E);

    // ---- layer 1 (+ fused layer-2 transform) ----
    w1t_kernel<<<128, 256, 0, stream>>>(W1, Wt);
    gemm1_kernel<<<(n + 127) / 128, 256, 0, stream>>>(x, Wt, h1b, n);
    agg1f_kernel<<<(n + 3) / 4, 256, 0, stream>>>(offs, deg, sEdge, h1b, dinv, b1, W2, h2b, n);

    // ---- layer 2 aggregation + log_softmax ----
    agg2_kernel<<<(n + 3) / 4, 256, 0, stream>>>(offs, deg, sEdge, h2b, dinv, b2, out, n);
}

// Round 5
// 695.924 us; speedup vs baseline: 1.0080x; 1.0080x over previous
//
#include <hip/hip_runtime.h>
#include <math.h>

// ---------------------------------------------------------------------------
// GCN 2-layer: h1 = relu(gcnconv(x,W1,b1)); out = log_softmax(gcnconv(h1,W2,b2))
// R5: agg kernels restructured for MLP: coalesced edge-record load + shfl
// broadcast + batch-8 independent gathers. gemm1 via bf16 MFMA; gemm2 fused
// into agg1 epilogue; h1,h2 bf16; CSR gather (no atomics in hot path).
// N=100000, E=1600000, F: 512 -> 64 -> 40
// ---------------------------------------------------------------------------

#define FIN 512
#define FHID 64
#define FOUT 40

typedef __attribute__((ext_vector_type(8))) short short8;
typedef __attribute__((ext_vector_type(4))) float f32x4;
typedef unsigned short ushort_t;
typedef unsigned int uint_t;

__device__ __forceinline__ ushort_t bf16_rn(float f) {
    union { float f; uint_t u; } v; v.f = f;
    uint_t r = v.u + 0x7FFF + ((v.u >> 16) & 1);
    return (ushort_t)(r >> 16);
}
__device__ __forceinline__ uint_t pack_bf16(float a, float b) {
    return (uint_t)bf16_rn(a) | ((uint_t)bf16_rn(b) << 16);
}
__device__ __forceinline__ float bf16_to_f(ushort_t u) {
    union { uint_t i; float f; } t; t.i = ((uint_t)u) << 16; return t.f;
}

// ---------------- histogram of in-degree ----------------
__global__ void hist_kernel(const int* __restrict__ col, int* __restrict__ deg, int E) {
    int e = blockIdx.x * 256 + threadIdx.x;
    if (e < E) atomicAdd(&deg[col[e]], 1);
}

__global__ void dinv_kernel(const int* __restrict__ deg, float* __restrict__ dinv, int n) {
    int i = blockIdx.x * 256 + threadIdx.x;
    if (i < n) dinv[i] = rsqrtf((float)deg[i] + 1.0f);
}

// ---------------- scan ----------------
__global__ void scan1_kernel(const int* __restrict__ deg, int* __restrict__ offs,
                             int* __restrict__ bsums, int n) {
    __shared__ int tmp[256];
    int tid = threadIdx.x;
    int i = blockIdx.x * 256 + tid;
    int v = (i < n) ? deg[i] : 0;
    tmp[tid] = v;
    __syncthreads();
    for (int off = 1; off < 256; off <<= 1) {
        int t = (tid >= off) ? tmp[tid - off] : 0;
        __syncthreads();
        tmp[tid] += t;
        __syncthreads();
    }
    if (i < n) offs[i] = tmp[tid] - v;
    if (tid == 255) bsums[blockIdx.x] = tmp[255];
}

__global__ void scan2_kernel(int* __restrict__ bsums, int nb) {
    __shared__ int tmp[512];
    int tid = threadIdx.x;
    int v = (tid < nb) ? bsums[tid] : 0;
    tmp[tid] = v;
    __syncthreads();
    for (int off = 1; off < 512; off <<= 1) {
        int t = (tid >= off) ? tmp[tid - off] : 0;
        __syncthreads();
        tmp[tid] += t;
        __syncthreads();
    }
    if (tid < nb) bsums[tid] = tmp[tid] - v;
}

__global__ void scan3_kernel(int* __restrict__ offs, const int* __restrict__ bsums,
                             int* __restrict__ cursor, int n) {
    int i = blockIdx.x * 256 + threadIdx.x;
    if (i < n) {
        int o = offs[i] + bsums[blockIdx.x];
        offs[i] = o;
        cursor[i] = o;
    }
}

// ---------------- build dest-sorted packed edge records {row, norm} ----------
__global__ void build_kernel(const int* __restrict__ row, const int* __restrict__ col,
                             const float* __restrict__ dinv, int* __restrict__ cursor,
                             uint2* __restrict__ sEdge, int E) {
    int e = blockIdx.x * 256 + threadIdx.x;
    if (e < E) {
        int r = row[e], c = col[e];
        float nm = dinv[r] * dinv[c];
        int pos = atomicAdd(&cursor[c], 1);
        sEdge[pos] = make_uint2((uint_t)r, __float_as_uint(nm));
    }
}

// ---------------- W1 transpose + bf16: Wt[n][k] = bf16(W1[k][n]) --------------
__global__ void w1t_kernel(const float* __restrict__ W1, ushort_t* __restrict__ Wt) {
    int idx = blockIdx.x * 256 + threadIdx.x;   // 32768
    int nrow = idx >> 9;
    int k = idx & 511;
    Wt[idx] = bf16_rn(W1[k * 64 + nrow]);
}

// ---------------- GEMM1 (MFMA): h1b[N,64] = bf16( x[N,512] @ W1[512,64] ) ----
#define LDA 72
#define LDB 72
__global__ __launch_bounds__(256) void gemm1_kernel(
    const float* __restrict__ x, const ushort_t* __restrict__ Wt,
    ushort_t* __restrict__ h1b, int n) {
    __shared__ ushort_t lA[128 * LDA];
    __shared__ ushort_t lB[64 * LDB];

    int tid = threadIdx.x;
    int wave = tid >> 6, lane = tid & 63;
    int quad = lane >> 4, m16 = lane & 15;
    int node0 = blockIdx.x * 128;

    f32x4 zero = {0.f, 0.f, 0.f, 0.f};
    f32x4 acc[2][4];
#pragma unroll
    for (int mt = 0; mt < 2; ++mt)
#pragma unroll
        for (int nt = 0; nt < 4; ++nt) acc[mt][nt] = zero;

    for (int kc = 0; kc < FIN; kc += 64) {
        __syncthreads();
#pragma unroll
        for (int i = 0; i < 8; ++i) {
            int p = tid + i * 256;
            int r = p >> 4;
            int k4 = p & 15;
            int node = node0 + r;
            float4 v = make_float4(0.f, 0.f, 0.f, 0.f);
            if (node < n) v = *reinterpret_cast<const float4*>(&x[(size_t)node * FIN + kc + k4 * 4]);
            uint2 u = make_uint2(pack_bf16(v.x, v.y), pack_bf16(v.z, v.w));
            *reinterpret_cast<uint2*>(&lA[r * LDA + k4 * 4]) = u;
        }
#pragma unroll
        for (int i = 0; i < 2; ++i) {
            int p = tid + i * 256;
            int nr = p >> 3;
            int seg = p & 7;
            uint4 v = *reinterpret_cast<const uint4*>(&Wt[(size_t)nr * FIN + kc + seg * 8]);
            *reinterpret_cast<uint4*>(&lB[nr * LDB + seg * 8]) = v;
        }
        __syncthreads();
#pragma unroll
        for (int kk = 0; kk < 2; ++kk) {
            short8 a[2], b[4];
#pragma unroll
            for (int mt = 0; mt < 2; ++mt)
                a[mt] = *reinterpret_cast<const short8*>(
                    &lA[(wave * 32 + mt * 16 + m16) * LDA + kk * 32 + quad * 8]);
#pragma unroll
            for (int nt = 0; nt < 4; ++nt)
                b[nt] = *reinterpret_cast<const short8*>(
                    &lB[(nt * 16 + m16) * LDB + kk * 32 + quad * 8]);
#pragma unroll
            for (int mt = 0; mt < 2; ++mt)
#pragma unroll
                for (int nt = 0; nt < 4; ++nt)
                    acc[mt][nt] = __builtin_amdgcn_mfma_f32_16x16x32_bf16(
                        a[mt], b[nt], acc[mt][nt], 0, 0, 0);
        }
    }

#pragma unroll
    for (int mt = 0; mt < 2; ++mt) {
#pragma unroll
        for (int reg = 0; reg < 4; ++reg) {
            int node = node0 + wave * 32 + mt * 16 + quad * 4 + reg;
            if (node < n) {
#pragma unroll
                for (int nt = 0; nt < 4; ++nt)
                    h1b[(size_t)node * 64 + nt * 16 + m16] = bf16_rn(acc[mt][nt][reg]);
            }
        }
    }
}

// ---------------- fused agg1 + self-loop + bias + relu + GEMM2 ----------------
// one wave per node; lane = hidden feature (64); edge records distributed by
// coalesced lane-load + shfl; gathers batched x8 for MLP.
__global__ __launch_bounds__(256) void agg1f_kernel(
    const int* __restrict__ offs, const int* __restrict__ deg,
    const uint2* __restrict__ sEdge, const ushort_t* __restrict__ h1b,
    const float* __restrict__ dinv, const float* __restrict__ b1,
    const float* __restrict__ W2, ushort_t* __restrict__ h2b, int n) {
    __shared__ float lw2[64 * FOUT + 64];
    int tid = threadIdx.x;
#pragma unroll
    for (int r = 0; r < 10; ++r) lw2[tid + r * 256] = W2[tid + r * 256];

    int lane = tid & 63;
    int node = blockIdx.x * 4 + (tid >> 6);
    bool valid = node < n;
    int start = valid ? offs[node] : 0;
    int cnt = valid ? deg[node] : 0;

    float ac[4] = {0.f, 0.f, 0.f, 0.f};
    for (int base = 0; base < cnt; base += 64) {
        int m = min(64, cnt - base);
        uint2 my = (lane < m) ? sEdge[start + base + lane] : make_uint2(0u, 0u);
        int   rr = (int)my.x;
        float nn = __uint_as_float(my.y);
        int k = 0;
        for (; k + 8 <= m; k += 8) {
            int r[8]; float nm[8], v[8];
#pragma unroll
            for (int u = 0; u < 8; ++u) {
                r[u]  = __shfl(rr, k + u);
                nm[u] = __shfl(nn, k + u);
            }
#pragma unroll
            for (int u = 0; u < 8; ++u)
                v[u] = bf16_to_f(h1b[(size_t)r[u] * 64 + lane]);
#pragma unroll
            for (int u = 0; u < 8; ++u)
                ac[u & 3] = fmaf(v[u], nm[u], ac[u & 3]);
        }
        for (; k < m; ++k) {
            int r = __shfl(rr, k);
            float nm = __shfl(nn, k);
            ac[k & 3] = fmaf(bf16_to_f(h1b[(size_t)r * 64 + lane]), nm, ac[k & 3]);
        }
    }

    float v = 0.f;
    if (valid) {
        float di = dinv[node];
        float acc = (ac[0] + ac[1]) + (ac[2] + ac[3]);
        v = fmaf(bf16_to_f(h1b[(size_t)node * 64 + lane]), di * di, acc) + b1[lane];
        v = fmaxf(v, 0.f);
    }

    __syncthreads();   // lw2 ready (all 256 threads alive)

    // h2[j] = sum_k h[k] * W2[k][j], j = lane (0..39 active)
    float o0 = 0.f, o1 = 0.f;
#pragma unroll
    for (int kk = 0; kk < 64; kk += 4) {
        float a0 = __shfl(v, kk), a1 = __shfl(v, kk + 1);
        float a2 = __shfl(v, kk + 2), a3 = __shfl(v, kk + 3);
        o0 = fmaf(a0, lw2[kk * FOUT + lane], o0);
        o1 = fmaf(a1, lw2[(kk + 1) * FOUT + lane], o1);
        o0 = fmaf(a2, lw2[(kk + 2) * FOUT + lane], o0);
        o1 = fmaf(a3, lw2[(kk + 3) * FOUT + lane], o1);
    }
    if (valid && lane < FOUT)
        h2b[(size_t)node * FOUT + lane] = bf16_rn(o0 + o1);
}

// ---------------- fused agg2 + self-loop + bias + log_softmax ----------------
__global__ __launch_bounds__(256) void agg2_kernel(
    const int* __restrict__ offs, const int* __restrict__ deg,
    const uint2* __restrict__ sEdge, const ushort_t* __restrict__ h2b,
    const float* __restrict__ dinv, const float* __restrict__ b2,
    float* __restrict__ out, int n) {
    int tid = threadIdx.x;
    int lane = tid & 63;
    int node = blockIdx.x * 4 + (tid >> 6);
    if (node >= n) return;            // wave-uniform; no block syncs below
    bool act = lane < FOUT;
    int start = offs[node];
    int cnt = deg[node];

    float ac[4] = {0.f, 0.f, 0.f, 0.f};
    for (int base = 0; base < cnt; base += 64) {
        int m = min(64, cnt - base);
        uint2 my = (lane < m) ? sEdge[start + base + lane] : make_uint2(0u, 0u);
        int   rr = (int)my.x;
        float nn = __uint_as_float(my.y);
        int k = 0;
        for (; k + 8 <= m; k += 8) {
            int r[8]; float nm[8], v[8];
#pragma unroll
            for (int u = 0; u < 8; ++u) {
                r[u]  = __shfl(rr, k + u);
                nm[u] = __shfl(nn, k + u);
            }
#pragma unroll
            for (int u = 0; u < 8; ++u)
                v[u] = act ? bf16_to_f(h2b[(size_t)r[u] * FOUT + lane]) : 0.f;
#pragma unroll
            for (int u = 0; u < 8; ++u)
                ac[u & 3] = fmaf(v[u], nm[u], ac[u & 3]);
        }
        for (; k < m; ++k) {
            int r = __shfl(rr, k);
            float nm = __shfl(nn, k);
            float v = act ? bf16_to_f(h2b[(size_t)r * FOUT + lane]) : 0.f;
            ac[k & 3] = fmaf(v, nm, ac[k & 3]);
        }
    }
    float acc = (ac[0] + ac[1]) + (ac[2] + ac[3]);
    float di = dinv[node];
    float dd = di * di;
    float raw = 0.f, v = -INFINITY;
    if (act) {
        raw = acc + bf16_to_f(h2b[(size_t)node * FOUT + lane]) * dd + b2[lane];
        v = raw;
    }
    float m = v;
#pragma unroll
    for (int off = 32; off > 0; off >>= 1) m = fmaxf(m, __shfl_down(m, off));
    m = __shfl(m, 0);
    float ex = act ? expf(raw - m) : 0.f;
    float s = ex;
#pragma unroll
    for (int off = 32; off > 0; off >>= 1) s += __shfl_down(s, off);
    s = __shfl(s, 0);
    float ls = logf(s);
    if (act) out[(size_t)node * FOUT + lane] = raw - m - ls;
}

// ---------------------------------------------------------------------------
extern "C" void kernel_launch(void* const* d_in, const int* in_sizes, int n_in,
                              void* d_out, int out_size, void* d_ws, size_t ws_size,
                              hipStream_t stream) {
    const float* x  = (const float*)d_in[0];
    const int*   ei = (const int*)d_in[1];
    const float* W1 = (const float*)d_in[2];
    const float* b1 = (const float*)d_in[3];
    const float* W2 = (const float*)d_in[4];
    const float* b2 = (const float*)d_in[5];
    float* out = (float*)d_out;

    int n = in_sizes[0] / FIN;        // 100000
    int E = in_sizes[1] / 2;          // 1600000
    const int* row = ei;
    const int* col = ei + E;

    // workspace layout (4-byte words), ~36 MB total
    int* wsi = (int*)d_ws;
    const size_t NR = 100352;
    int*      deg    = wsi;                                  // [NR]
    float*    dinv   = (float*)(wsi + NR);                   // [NR]
    int*      offs   = wsi + 2 * NR;                         // [NR]
    int*      cursor = wsi + 3 * NR;                         // [NR]
    int*      bsums  = wsi + 4 * NR;                         // [512]
    ushort_t* Wt     = (ushort_t*)(wsi + 4 * NR + 512);      // [64*512] bf16
    uint2*    sEdge  = (uint2*)(wsi + 4 * NR + 512 + 16384); // [E] {row,norm}
    ushort_t* h1b    = (ushort_t*)(sEdge + (size_t)E);       // [n*64] bf16
    ushort_t* h2b    = h1b + (size_t)n * 64;                 // [n*40] bf16

    int nb = (n + 255) / 256;   // 391

    // ---- CSR build ----
    hipMemsetAsync(deg, 0, (size_t)n * 4, stream);
    hist_kernel<<<(E + 255) / 256, 256, 0, stream>>>(col, deg, E);
    dinv_kernel<<<nb, 256, 0, stream>>>(deg, dinv, n);
    scan1_kernel<<<nb, 256, 0, stream>>>(deg, offs, bsums, n);
    scan2_kernel<<<1, 512, 0, stream>>>(bsums, nb);
    scan3_kernel<<<nb, 256, 0, stream>>>(offs, bsums, cursor, n);
    build_kernel<<<(E + 255) / 256, 256, 0, stream>>>(row, col, dinv, cursor, sEdge, E);

    // ---- layer 1 (+ fused layer-2 transform) ----
    w1t_kernel<<<128, 256, 0, stream>>>(W1, Wt);
    gemm1_kernel<<<(n + 127) / 128, 256, 0, stream>>>(x, Wt, h1b, n);
    agg1f_kernel<<<(n + 3) / 4, 256, 0, stream>>>(offs, deg, sEdge, h1b, dinv, b1, W2, h2b, n);

    // ---- layer 2 aggregation + log_softmax ----
    agg2_kernel<<<(n + 3) / 4, 256, 0, stream>>>(offs, deg, sEdge, h2b, dinv, b2, out, n);
}

// Round 6
// 646.537 us; speedup vs baseline: 1.0850x; 1.0764x over previous
//
#include <hip/hip_runtime.h>
#include <math.h>

// ---------------------------------------------------------------------------
// GCN 2-layer: h1 = relu(gcnconv(x,W1,b1)); out = log_softmax(gcnconv(h1,W2,b2))
// R6: agg kernels use 8-edges x 8-lanes x 16B vectorized gathers (1 KB/instr),
// chunk-16 with masked records, shfl-xor cross-edge reduction per node.
// sEdge.y = dinv[row]; dinv[col] applied once per node (linearity).
// gemm1 via bf16 MFMA; gemm2 fused into agg1 epilogue; h1,h2 bf16.
// N=100000, E=1600000, F: 512 -> 64 -> 40
// ---------------------------------------------------------------------------

#define FIN 512
#define FHID 64
#define FOUT 40

typedef __attribute__((ext_vector_type(8))) short short8;
typedef __attribute__((ext_vector_type(4))) float f32x4;
typedef unsigned short ushort_t;
typedef unsigned int uint_t;

__device__ __forceinline__ ushort_t bf16_rn(float f) {
    union { float f; uint_t u; } v; v.f = f;
    uint_t r = v.u + 0x7FFF + ((v.u >> 16) & 1);
    return (ushort_t)(r >> 16);
}
__device__ __forceinline__ uint_t pack_bf16(float a, float b) {
    return (uint_t)bf16_rn(a) | ((uint_t)bf16_rn(b) << 16);
}
__device__ __forceinline__ float bf16_to_f(ushort_t u) {
    union { uint_t i; float f; } t; t.i = ((uint_t)u) << 16; return t.f;
}
// accumulate 8 bf16 feats (one uint4) * nm into acc[8]
__device__ __forceinline__ void acc8(float* acc, uint4 g, float nm) {
    acc[0] = fmaf(__uint_as_float(g.x << 16), nm, acc[0]);
    acc[1] = fmaf(__uint_as_float(g.x & 0xFFFF0000u), nm, acc[1]);
    acc[2] = fmaf(__uint_as_float(g.y << 16), nm, acc[2]);
    acc[3] = fmaf(__uint_as_float(g.y & 0xFFFF0000u), nm, acc[3]);
    acc[4] = fmaf(__uint_as_float(g.z << 16), nm, acc[4]);
    acc[5] = fmaf(__uint_as_float(g.z & 0xFFFF0000u), nm, acc[5]);
    acc[6] = fmaf(__uint_as_float(g.w << 16), nm, acc[6]);
    acc[7] = fmaf(__uint_as_float(g.w & 0xFFFF0000u), nm, acc[7]);
}
__device__ __forceinline__ void unpack8(float* d, uint4 g) {
    d[0] = __uint_as_float(g.x << 16); d[1] = __uint_as_float(g.x & 0xFFFF0000u);
    d[2] = __uint_as_float(g.y << 16); d[3] = __uint_as_float(g.y & 0xFFFF0000u);
    d[4] = __uint_as_float(g.z << 16); d[5] = __uint_as_float(g.z & 0xFFFF0000u);
    d[6] = __uint_as_float(g.w << 16); d[7] = __uint_as_float(g.w & 0xFFFF0000u);
}

// ---------------- histogram of in-degree (x4 vectorized) ----------------
__global__ void hist_kernel(const int* __restrict__ col, int* __restrict__ deg, int E) {
    int i = (blockIdx.x * 256 + threadIdx.x) * 4;
    if (i + 3 < E) {
        int4 c = *reinterpret_cast<const int4*>(&col[i]);
        atomicAdd(&deg[c.x], 1); atomicAdd(&deg[c.y], 1);
        atomicAdd(&deg[c.z], 1); atomicAdd(&deg[c.w], 1);
    } else {
        for (int j = i; j < E; ++j) atomicAdd(&deg[col[j]], 1);
    }
}

__global__ void dinv_kernel(const int* __restrict__ deg, float* __restrict__ dinv, int n) {
    int i = blockIdx.x * 256 + threadIdx.x;
    if (i < n) dinv[i] = rsqrtf((float)deg[i] + 1.0f);
}

// ---------------- scan ----------------
__global__ void scan1_kernel(const int* __restrict__ deg, int* __restrict__ offs,
                             int* __restrict__ bsums, int n) {
    __shared__ int tmp[256];
    int tid = threadIdx.x;
    int i = blockIdx.x * 256 + tid;
    int v = (i < n) ? deg[i] : 0;
    tmp[tid] = v;
    __syncthreads();
    for (int off = 1; off < 256; off <<= 1) {
        int t = (tid >= off) ? tmp[tid - off] : 0;
        __syncthreads();
        tmp[tid] += t;
        __syncthreads();
    }
    if (i < n) offs[i] = tmp[tid] - v;
    if (tid == 255) bsums[blockIdx.x] = tmp[255];
}

__global__ void scan2_kernel(int* __restrict__ bsums, int nb) {
    __shared__ int tmp[512];
    int tid = threadIdx.x;
    int v = (tid < nb) ? bsums[tid] : 0;
    tmp[tid] = v;
    __syncthreads();
    for (int off = 1; off < 512; off <<= 1) {
        int t = (tid >= off) ? tmp[tid - off] : 0;
        __syncthreads();
        tmp[tid] += t;
        __syncthreads();
    }
    if (tid < nb) bsums[tid] = tmp[tid] - v;
}

__global__ void scan3_kernel(int* __restrict__ offs, const int* __restrict__ bsums,
                             int* __restrict__ cursor, int n) {
    int i = blockIdx.x * 256 + threadIdx.x;
    if (i < n) {
        int o = offs[i] + bsums[blockIdx.x];
        offs[i] = o;
        cursor[i] = o;
    }
}

// ---------------- build dest-sorted records {row, dinv[row]} ----------------
__global__ void build_kernel(const int* __restrict__ row, const int* __restrict__ col,
                             const float* __restrict__ dinv, int* __restrict__ cursor,
                             uint2* __restrict__ sEdge, int E) {
    int e = blockIdx.x * 256 + threadIdx.x;
    if (e < E) {
        int r = row[e], c = col[e];
        float nm = dinv[r];                       // dinv[c] applied per-node later
        int pos = atomicAdd(&cursor[c], 1);
        sEdge[pos] = make_uint2((uint_t)r, __float_as_uint(nm));
    }
}

// ---------------- W1 transpose + bf16 ----------------
__global__ void w1t_kernel(const float* __restrict__ W1, ushort_t* __restrict__ Wt) {
    int idx = blockIdx.x * 256 + threadIdx.x;   // 32768
    int nrow = idx >> 9;
    int k = idx & 511;
    Wt[idx] = bf16_rn(W1[k * 64 + nrow]);
}

// ---------------- GEMM1 (MFMA): h1b[N,64] = bf16( x[N,512] @ W1[512,64] ) ----
#define LDA 72
#define LDB 72
__global__ __launch_bounds__(256) void gemm1_kernel(
    const float* __restrict__ x, const ushort_t* __restrict__ Wt,
    ushort_t* __restrict__ h1b, int n) {
    __shared__ ushort_t lA[128 * LDA];
    __shared__ ushort_t lB[64 * LDB];

    int tid = threadIdx.x;
    int wave = tid >> 6, lane = tid & 63;
    int quad = lane >> 4, m16 = lane & 15;
    int node0 = blockIdx.x * 128;

    f32x4 zero = {0.f, 0.f, 0.f, 0.f};
    f32x4 acc[2][4];
#pragma unroll
    for (int mt = 0; mt < 2; ++mt)
#pragma unroll
        for (int nt = 0; nt < 4; ++nt) acc[mt][nt] = zero;

    for (int kc = 0; kc < FIN; kc += 64) {
        __syncthreads();
#pragma unroll
        for (int i = 0; i < 8; ++i) {
            int p = tid + i * 256;
            int r = p >> 4;
            int k4 = p & 15;
            int node = node0 + r;
            float4 v = make_float4(0.f, 0.f, 0.f, 0.f);
            if (node < n) v = *reinterpret_cast<const float4*>(&x[(size_t)node * FIN + kc + k4 * 4]);
            uint2 u = make_uint2(pack_bf16(v.x, v.y), pack_bf16(v.z, v.w));
            *reinterpret_cast<uint2*>(&lA[r * LDA + k4 * 4]) = u;
        }
#pragma unroll
        for (int i = 0; i < 2; ++i) {
            int p = tid + i * 256;
            int nr = p >> 3;
            int seg = p & 7;
            uint4 v = *reinterpret_cast<const uint4*>(&Wt[(size_t)nr * FIN + kc + seg * 8]);
            *reinterpret_cast<uint4*>(&lB[nr * LDB + seg * 8]) = v;
        }
        __syncthreads();
#pragma unroll
        for (int kk = 0; kk < 2; ++kk) {
            short8 a[2], b[4];
#pragma unroll
            for (int mt = 0; mt < 2; ++mt)
                a[mt] = *reinterpret_cast<const short8*>(
                    &lA[(wave * 32 + mt * 16 + m16) * LDA + kk * 32 + quad * 8]);
#pragma unroll
            for (int nt = 0; nt < 4; ++nt)
                b[nt] = *reinterpret_cast<const short8*>(
                    &lB[(nt * 16 + m16) * LDB + kk * 32 + quad * 8]);
#pragma unroll
            for (int mt = 0; mt < 2; ++mt)
#pragma unroll
                for (int nt = 0; nt < 4; ++nt)
                    acc[mt][nt] = __builtin_amdgcn_mfma_f32_16x16x32_bf16(
                        a[mt], b[nt], acc[mt][nt], 0, 0, 0);
        }
    }

#pragma unroll
    for (int mt = 0; mt < 2; ++mt) {
#pragma unroll
        for (int reg = 0; reg < 4; ++reg) {
            int node = node0 + wave * 32 + mt * 16 + quad * 4 + reg;
            if (node < n) {
#pragma unroll
                for (int nt = 0; nt < 4; ++nt)
                    h1b[(size_t)node * 64 + nt * 16 + m16] = bf16_rn(acc[mt][nt][reg]);
            }
        }
    }
}

// ---------------- fused agg1 + self-loop + bias + relu + GEMM2 ----------------
// wave = node; layout: 8 edges x 8 lanes x 16B gathers; cross-edge shfl-xor
// reduce; epilogue redistributes via LDS then shfl matvec into W2.
__global__ __launch_bounds__(256) void agg1f_kernel(
    const int* __restrict__ offs, const int* __restrict__ deg,
    const uint2* __restrict__ sEdge, const ushort_t* __restrict__ h1b,
    const float* __restrict__ dinv, const float* __restrict__ b1,
    const float* __restrict__ W2, ushort_t* __restrict__ h2b, int n) {
    __shared__ float lw2[64 * FOUT];
    __shared__ float lb1[64];
    __shared__ float lh[4][64];
    int tid = threadIdx.x;
#pragma unroll
    for (int r = 0; r < 10; ++r) lw2[tid + r * 256] = W2[tid + r * 256];
    if (tid < 64) lb1[tid] = b1[tid];

    int wv = tid >> 6, lane = tid & 63;
    int e8 = lane >> 3, c = lane & 7;
    int node = blockIdx.x * 4 + wv;
    bool valid = node < n;
    int start = valid ? offs[node] : 0;
    int cnt = valid ? deg[node] : 0;

    float acc[8];
#pragma unroll
    for (int j = 0; j < 8; ++j) acc[j] = 0.f;

    for (int base = 0; base < cnt; base += 16) {
        int i0 = base + e8, i1 = i0 + 8;
        uint2 e0 = (i0 < cnt) ? sEdge[start + i0] : make_uint2(0u, 0u);
        uint2 e1 = (i1 < cnt) ? sEdge[start + i1] : make_uint2(0u, 0u);
        uint4 g0 = *reinterpret_cast<const uint4*>(&h1b[(size_t)e0.x * 64 + c * 8]);
        uint4 g1 = *reinterpret_cast<const uint4*>(&h1b[(size_t)e1.x * 64 + c * 8]);
        acc8(acc, g0, __uint_as_float(e0.y));
        acc8(acc, g1, __uint_as_float(e1.y));
    }
#pragma unroll
    for (int mask = 8; mask <= 32; mask <<= 1)
#pragma unroll
        for (int j = 0; j < 8; ++j) acc[j] += __shfl_xor(acc[j], mask);

    if (valid && e8 == 0) {
        *reinterpret_cast<float4*>(&lh[wv][c * 8]) =
            make_float4(acc[0], acc[1], acc[2], acc[3]);
        *reinterpret_cast<float4*>(&lh[wv][c * 8 + 4]) =
            make_float4(acc[4], acc[5], acc[6], acc[7]);
    }
    __syncthreads();

    float v = 0.f;
    if (valid) {
        float di = dinv[node];
        float self = bf16_to_f(h1b[(size_t)node * 64 + lane]) * di;
        v = fmaxf(fmaf(lh[wv][lane] + self, di, lb1[lane]), 0.f);
    }

    // h2[j] = sum_k v[k] * W2[k][j], j = lane (0..39 active)
    float o0 = 0.f, o1 = 0.f;
#pragma unroll
    for (int kk = 0; kk < 64; kk += 4) {
        float a0 = __shfl(v, kk), a1 = __shfl(v, kk + 1);
        float a2 = __shfl(v, kk + 2), a3 = __shfl(v, kk + 3);
        o0 = fmaf(a0, lw2[kk * FOUT + lane], o0);
        o1 = fmaf(a1, lw2[(kk + 1) * FOUT + lane], o1);
        o0 = fmaf(a2, lw2[(kk + 2) * FOUT + lane], o0);
        o1 = fmaf(a3, lw2[(kk + 3) * FOUT + lane], o1);
    }
    if (valid && lane < FOUT)
        h2b[(size_t)node * FOUT + lane] = bf16_rn(o0 + o1);
}

// ---------------- fused agg2 + self-loop + bias + log_softmax ----------------
// wave = node; 8 edges x (5 of 8) lanes x 16B gathers over 40-wide bf16 rows.
__global__ __launch_bounds__(256) void agg2_kernel(
    const int* __restrict__ offs, const int* __restrict__ deg,
    const uint2* __restrict__ sEdge, const ushort_t* __restrict__ h2b,
    const float* __restrict__ dinv, const float* __restrict__ b2,
    float* __restrict__ out, int n) {
    __shared__ float lb2[40];
    int tid = threadIdx.x;
    if (tid < 40) lb2[tid] = b2[tid];
    __syncthreads();

    int wv = tid >> 6, lane = tid & 63;
    int e8 = lane >> 3, c = lane & 7;
    bool act = c < 5;
    int co = (act ? c : 4) * 8;           // clamped chunk offset (feats)
    int node = blockIdx.x * 4 + wv;
    if (node >= n) return;                // wave-uniform; barrier already passed
    int start = offs[node];
    int cnt = deg[node];

    float acc[8];
#pragma unroll
    for (int j = 0; j < 8; ++j) acc[j] = 0.f;

    for (int base = 0; base < cnt; base += 16) {
        int i0 = base + e8, i1 = i0 + 8;
        uint2 e0 = (i0 < cnt) ? sEdge[start + i0] : make_uint2(0u, 0u);
        uint2 e1 = (i1 < cnt) ? sEdge[start + i1] : make_uint2(0u, 0u);
        uint4 g0 = *reinterpret_cast<const uint4*>(&h2b[(size_t)e0.x * FOUT + co]);
        uint4 g1 = *reinterpret_cast<const uint4*>(&h2b[(size_t)e1.x * FOUT + co]);
        acc8(acc, g0, __uint_as_float(e0.y));
        acc8(acc, g1, __uint_as_float(e1.y));
    }
#pragma unroll
    for (int mask = 8; mask <= 32; mask <<= 1)
#pragma unroll
        for (int j = 0; j < 8; ++j) acc[j] += __shfl_xor(acc[j], mask);

    float di = dinv[node];
    uint4 sg = *reinterpret_cast<const uint4*>(&h2b[(size_t)node * FOUT + co]);
    float self[8];
    unpack8(self, sg);
    float raw[8];
#pragma unroll
    for (int j = 0; j < 8; ++j)
        raw[j] = fmaf(acc[j] + self[j] * di, di, lb2[co + j]);

    float pm = -INFINITY;
    if (act) {
#pragma unroll
        for (int j = 0; j < 8; ++j) pm = fmaxf(pm, raw[j]);
    }
#pragma unroll
    for (int mask = 1; mask <= 4; mask <<= 1) pm = fmaxf(pm, __shfl_xor(pm, mask));
    float s = 0.f;
    if (act) {
#pragma unroll
        for (int j = 0; j < 8; ++j) s += expf(raw[j] - pm);
    }
#pragma unroll
    for (int mask = 1; mask <= 4; mask <<= 1) s += __shfl_xor(s, mask);
    float ls = logf(s) + pm;

    if (act && e8 == 0) {
        float* op = &out[(size_t)node * FOUT + co];
        *reinterpret_cast<float4*>(op) =
            make_float4(raw[0] - ls, raw[1] - ls, raw[2] - ls, raw[3] - ls);
        *reinterpret_cast<float4*>(op + 4) =
            make_float4(raw[4] - ls, raw[5] - ls, raw[6] - ls, raw[7] - ls);
    }
}

// ---------------------------------------------------------------------------
extern "C" void kernel_launch(void* const* d_in, const int* in_sizes, int n_in,
                              void* d_out, int out_size, void* d_ws, size_t ws_size,
                              hipStream_t stream) {
    const float* x  = (const float*)d_in[0];
    const int*   ei = (const int*)d_in[1];
    const float* W1 = (const float*)d_in[2];
    const float* b1 = (const float*)d_in[3];
    const float* W2 = (const float*)d_in[4];
    const float* b2 = (const float*)d_in[5];
    float* out = (float*)d_out;

    int n = in_sizes[0] / FIN;        // 100000
    int E = in_sizes[1] / 2;          // 1600000
    const int* row = ei;
    const int* col = ei + E;

    // workspace layout (4-byte words), ~36 MB total
    int* wsi = (int*)d_ws;
    const size_t NR = 100352;
    int*      deg    = wsi;                                  // [NR]
    float*    dinv   = (float*)(wsi + NR);                   // [NR]
    int*      offs   = wsi + 2 * NR;                         // [NR]
    int*      cursor = wsi + 3 * NR;                         // [NR]
    int*      bsums  = wsi + 4 * NR;                         // [512]
    ushort_t* Wt     = (ushort_t*)(wsi + 4 * NR + 512);      // [64*512] bf16
    uint2*    sEdge  = (uint2*)(wsi + 4 * NR + 512 + 16384); // [E] {row, dinv[row]}
    ushort_t* h1b    = (ushort_t*)(sEdge + (size_t)E);       // [n*64] bf16
    ushort_t* h2b    = h1b + (size_t)n * 64;                 // [n*40] bf16

    int nb = (n + 255) / 256;   // 391

    // ---- CSR build ----
    hipMemsetAsync(deg, 0, (size_t)n * 4, stream);
    hist_kernel<<<(E / 4 + 255) / 256, 256, 0, stream>>>(col, deg, E);
    dinv_kernel<<<nb, 256, 0, stream>>>(deg, dinv, n);
    scan1_kernel<<<nb, 256, 0, stream>>>(deg, offs, bsums, n);
    scan2_kernel<<<1, 512, 0, stream>>>(bsums, nb);
    scan3_kernel<<<nb, 256, 0, stream>>>(offs, bsums, cursor, n);
    build_kernel<<<(E + 255) / 256, 256, 0, stream>>>(row, col, dinv, cursor, sEdge, E);

    // ---- layer 1 (+ fused layer-2 transform) ----
    w1t_kernel<<<128, 256, 0, stream>>>(W1, Wt);
    gemm1_kernel<<<(n + 127) / 128, 256, 0, stream>>>(x, Wt, h1b, n);
    agg1f_kernel<<<(n + 3) / 4, 256, 0, stream>>>(offs, deg, sEdge, h1b, dinv, b1, W2, h2b, n);

    // ---- layer 2 aggregation + log_softmax ----
    agg2_kernel<<<(n + 3) / 4, 256, 0, stream>>>(offs, deg, sEdge, h2b, dinv, b2, out, n);
}